// Round 2
// baseline (503.839 us; speedup 1.0000x reference)
//
#include <hip/hip_runtime.h>

#define SEQ 512
#define EMB 8
#define NFAC 4

__device__ __forceinline__ float rfl(float v) {
    return __int_as_float(__builtin_amdgcn_readfirstlane(__float_as_int(v)));
}

// ---------------------------------------------------------------------------
// ws layout (floats):
//   wkq  [0..63]    folded cross-attn query·Wk rows: scores[p][s]=wkq[p]·x[s]+csb[p]
//   csb  [64..71]
//   M0   [72..135]  Wout[:,0:4]·Wv0  (8x8)  -> qcr = bo + M0·u_f + M1·u_{4+f}
//   M1   [136..199] Wout[:,4:8]·Wv1  (8x8)     where u_p = (Σ_s e_p(s)·x_s)/Σ_s e_p(s)
//   bo   [200..207] ca_b_out + Wout·bv
// ---------------------------------------------------------------------------
__global__ void precompute_kernel(
    const float* __restrict__ Q,
    const float* __restrict__ sa_w_in, const float* __restrict__ sa_b_in,
    const float* __restrict__ sa_w_out, const float* __restrict__ sa_b_out,
    const float* __restrict__ ca_w_in, const float* __restrict__ ca_b_in,
    const float* __restrict__ ca_w_out, const float* __restrict__ ca_b_out,
    float* __restrict__ ws)
{
    const int t = threadIdx.x;
    __shared__ float sw[608];
    __shared__ float sqh[32], skh[32], svh[32], sctx[32], sQu[32], sqc[32];
    enum { OQ = 0, SWIN = 32, SBIN = 224, SWOUT = 248, SBOUT = 312,
           CWIN = 320, CBIN = 512, CWOUT = 536, CBOUT = 600 };

    for (int i = t; i < 32;  i += 64) sw[OQ + i]    = Q[i];
    for (int i = t; i < 192; i += 64) sw[SWIN + i]  = sa_w_in[i];
    for (int i = t; i < 24;  i += 64) sw[SBIN + i]  = sa_b_in[i];
    for (int i = t; i < 64;  i += 64) sw[SWOUT + i] = sa_w_out[i];
    if (t < 8) sw[SBOUT + t] = sa_b_out[t];
    for (int i = t; i < 192; i += 64) sw[CWIN + i]  = ca_w_in[i];
    for (int i = t; i < 24;  i += 64) sw[CBIN + i]  = ca_b_in[i];
    for (int i = t; i < 64;  i += 64) sw[CWOUT + i] = ca_w_out[i];
    if (t < 8) sw[CBOUT + t] = ca_b_out[t];
    __syncthreads();

    // M0/M1/bo — independent of the self-attention result.
    {
        const int e2 = t >> 3, e = t & 7;
        float m0 = 0.f, m1 = 0.f;
        #pragma unroll
        for (int d = 0; d < 4; ++d) {
            m0 += sw[CWOUT + e2 * 8 + d]     * sw[CWIN + (16 + d) * 8 + e];
            m1 += sw[CWOUT + e2 * 8 + 4 + d] * sw[CWIN + (20 + d) * 8 + e];
        }
        ws[72 + t]  = m0;
        ws[136 + t] = m1;
    }
    if (t < 8) {
        float a = sw[CBOUT + t];
        #pragma unroll
        for (int d = 0; d < 8; ++d) a += sw[CWOUT + t * 8 + d] * sw[CBIN + 16 + d];
        ws[200 + t] = a;
    }

    // self-attn projections qh/kh/vh: 32 lanes, one (l,j) each
    if (t < 32) {
        const int l = t >> 3, j = t & 7;
        float aq = sw[SBIN + j], ak = sw[SBIN + 8 + j], av = sw[SBIN + 16 + j];
        #pragma unroll
        for (int e = 0; e < 8; ++e) {
            const float q = sw[OQ + l * 8 + e];
            aq += q * sw[SWIN + j * 8 + e];
            ak += q * sw[SWIN + (8 + j) * 8 + e];
            av += q * sw[SWIN + (16 + j) * 8 + e];
        }
        sqh[t] = aq; skh[t] = ak; svh[t] = av;
    }
    __syncthreads();

    // per-(h,l) softmax over the 4 keys + context
    if (t < 8) {
        const int h = t >> 2, l = t & 3;
        float sc[4], mx = -1e30f;
        #pragma unroll
        for (int m = 0; m < 4; ++m) {
            float a = 0.f;
            #pragma unroll
            for (int d = 0; d < 4; ++d) a += sqh[l * 8 + h * 4 + d] * skh[m * 8 + h * 4 + d];
            sc[m] = 0.5f * a;
            mx = fmaxf(mx, sc[m]);
        }
        float ssum = 0.f;
        #pragma unroll
        for (int m = 0; m < 4; ++m) { sc[m] = __expf(sc[m] - mx); ssum += sc[m]; }
        const float inv = 1.f / ssum;
        #pragma unroll
        for (int d = 0; d < 4; ++d) {
            float a = 0.f;
            #pragma unroll
            for (int m = 0; m < 4; ++m) a += sc[m] * svh[m * 8 + h * 4 + d];
            sctx[l * 8 + h * 4 + d] = a * inv;
        }
    }
    __syncthreads();

    // Qu = ctx @ sa_w_out^T + sa_b_out
    if (t < 32) {
        const int l = t >> 3, e2 = t & 7;
        float a = sw[SBOUT + e2];
        #pragma unroll
        for (int e = 0; e < 8; ++e) a += sctx[l * 8 + e] * sw[SWOUT + e2 * 8 + e];
        sQu[l * 8 + e2] = a;
    }
    __syncthreads();

    // qc = Qu @ Wq_ca^T + bq_ca
    if (t < 32) {
        const int l = t >> 3, j = t & 7;
        float a = sw[CBIN + j];
        #pragma unroll
        for (int e = 0; e < 8; ++e) a += sQu[l * 8 + e] * sw[CWIN + j * 8 + e];
        sqc[l * 8 + j] = a;
    }
    __syncthreads();

    // wkq[p][e] and csb[p]
    {
        const int p = t >> 3, e = t & 7, h = p >> 2, f = p & 3;
        float a = 0.f;
        #pragma unroll
        for (int d = 0; d < 4; ++d)
            a += sqc[f * 8 + h * 4 + d] * sw[CWIN + (8 + h * 4 + d) * 8 + e];
        ws[p * 8 + e] = 0.5f * a;
    }
    if (t < 8) {
        const int p = t, h = p >> 2, f = p & 3;
        float a = 0.f;
        #pragma unroll
        for (int d = 0; d < 4; ++d) a += sqc[f * 8 + h * 4 + d] * sw[CBIN + 8 + h * 4 + d];
        ws[64 + p] = 0.5f * a;
    }
}

// ---------------------------------------------------------------------------
// Main fused kernel: one block per batch, 256 threads = 4 waves.
// Wave w owns cross-score rows p={2w,2w+1}, then sim row f=w.
// No register x-cache: phase C re-reads x (L2/L3-hot) to keep VGPR <= 64
// (8 waves/SIMD). Score weights forced to SGPR via readfirstlane.
// Reductions: two-stage (intra-8 butterfly, cndmask element-select by lane&7,
// cross-group butterfly on 2 values) — 99 shuffles instead of 162.
// ---------------------------------------------------------------------------
__global__ __launch_bounds__(256, 8) void fused_kernel(
    const float* __restrict__ x,
    const float* __restrict__ r_w1, const float* __restrict__ r_b1,
    const float* __restrict__ r_w2, const float* __restrict__ r_b2,
    const float* __restrict__ ws,
    float* __restrict__ out, float* __restrict__ sim_out)
{
    const int b = blockIdx.x;
    const int tid = threadIdx.x;
    const int w = __builtin_amdgcn_readfirstlane(tid >> 6);
    const int lane = tid & 63;
    const int c7 = lane & 7;

    __shared__ float su[64];    // normalized u rows [p][e]
    __shared__ float sff[32];   // final_factors [f][e]

    const float* xb = x + (size_t)b * (SEQ * EMB);

    // wave-uniform score weights -> SGPRs (forced scalar)
    const int p0 = 2 * w, p1 = 2 * w + 1;
    float wq0[8], wq1[8];
    #pragma unroll
    for (int e = 0; e < 8; ++e) {
        wq0[e] = rfl(ws[p0 * 8 + e]);
        wq1[e] = rfl(ws[p1 * 8 + e]);
    }
    const float cb0 = rfl(ws[64 + p0]), cb1 = rfl(ws[64 + p1]);

    // ---- phase A: x load + cross scores + exp + weighted-x accumulation
    float xa0[8] = {0.f,0.f,0.f,0.f,0.f,0.f,0.f,0.f};
    float xa1[8] = {0.f,0.f,0.f,0.f,0.f,0.f,0.f,0.f};
    float sum0 = 0.f, sum1 = 0.f;
    #pragma unroll
    for (int j = 0; j < 8; ++j) {
        const int s = lane + 64 * j;
        const float4* xp = (const float4*)(xb + s * 8);
        float4 lo = xp[0], hi = xp[1];
        float xv[8] = {lo.x, lo.y, lo.z, lo.w, hi.x, hi.y, hi.z, hi.w};
        float sc0 = cb0, sc1 = cb1;
        #pragma unroll
        for (int e = 0; e < 8; ++e) { sc0 += wq0[e] * xv[e]; sc1 += wq1[e] * xv[e]; }
        const float e0 = __expf(sc0), e1 = __expf(sc1);
        sum0 += e0; sum1 += e1;
        #pragma unroll
        for (int e = 0; e < 8; ++e) {
            xa0[e] += e0 * xv[e];
            xa1[e] += e1 * xv[e];
        }
    }
    // two-stage reduction: intra-group-of-8 for all accumulators
    #pragma unroll
    for (int m = 1; m < 8; m <<= 1) {
        sum0 += __shfl_xor(sum0, m, 64);
        sum1 += __shfl_xor(sum1, m, 64);
        #pragma unroll
        for (int e = 0; e < 8; ++e) {
            xa0[e] += __shfl_xor(xa0[e], m, 64);
            xa1[e] += __shfl_xor(xa1[e], m, 64);
        }
    }
    // element-select by lane&7 (compile-time indices only)
    float v0 = xa0[0], v1 = xa1[0];
    #pragma unroll
    for (int e = 1; e < 8; ++e) {
        v0 = (c7 == e) ? xa0[e] : v0;
        v1 = (c7 == e) ? xa1[e] : v1;
    }
    // cross-group butterfly (masks 8,16,32) on 4 values
    #pragma unroll
    for (int m = 8; m < 64; m <<= 1) {
        sum0 += __shfl_xor(sum0, m, 64);
        sum1 += __shfl_xor(sum1, m, 64);
        v0 += __shfl_xor(v0, m, 64);
        v1 += __shfl_xor(v1, m, 64);
    }
    if (lane < 8) {
        su[p0 * 8 + lane] = v0 / sum0;
        su[p1 * 8 + lane] = v1 / sum1;
    }
    __syncthreads();

    // ---- phase B: qcr row f=w via folded M0/M1 (8 rows computed, shfl bcast)
    float u0[8], u1[8];
    #pragma unroll
    for (int e = 0; e < 8; ++e) { u0[e] = su[w * 8 + e]; u1[e] = su[32 + w * 8 + e]; }
    float qv = ws[200 + c7];
    #pragma unroll
    for (int e = 0; e < 8; ++e)
        qv += ws[72 + c7 * 8 + e] * u0[e] + ws[136 + c7 * 8 + e] * u1[e];
    float qcr[8];
    #pragma unroll
    for (int e = 0; e < 8; ++e) qcr[e] = __shfl(qv, e, 64);

    // ---- phase C: similarity row f=w (x re-read, L2-hot), fused softmax + ff
    float facc[8] = {0.f,0.f,0.f,0.f,0.f,0.f,0.f,0.f};
    float fsum = 0.f;
    float* simb = sim_out + (size_t)b * (NFAC * SEQ) + w * SEQ;
    #pragma unroll
    for (int j = 0; j < 8; ++j) {
        const int s = lane + 64 * j;
        const float4* xp = (const float4*)(xb + s * 8);
        float4 lo = xp[0], hi = xp[1];
        float xv[8] = {lo.x, lo.y, lo.z, lo.w, hi.x, hi.y, hi.z, hi.w};
        float sim = 0.f;
        #pragma unroll
        for (int e = 0; e < 8; ++e) sim += qcr[e] * xv[e];
        simb[s] = sim;
        const float ez = __expf(sim);
        fsum += ez;
        #pragma unroll
        for (int e = 0; e < 8; ++e) facc[e] += ez * xv[e];
    }
    #pragma unroll
    for (int m = 1; m < 8; m <<= 1) {
        fsum += __shfl_xor(fsum, m, 64);
        #pragma unroll
        for (int e = 0; e < 8; ++e) facc[e] += __shfl_xor(facc[e], m, 64);
    }
    float fv = facc[0];
    #pragma unroll
    for (int e = 1; e < 8; ++e) fv = (c7 == e) ? facc[e] : fv;
    #pragma unroll
    for (int m = 8; m < 64; m <<= 1) {
        fsum += __shfl_xor(fsum, m, 64);
        fv += __shfl_xor(fv, m, 64);
    }
    if (lane < 8) sff[w * 8 + lane] = fv / fsum;
    __syncthreads();

    // ---- phase D: tiny MLP (wave 0, lanes 0..15), out[b]
    if (tid < 16) {
        float a = r_b1[tid];
        const float4* w1p = (const float4*)(r_w1 + tid * 32);
        #pragma unroll
        for (int k = 0; k < 8; ++k) {
            float4 ww = w1p[k];
            a += ww.x * sff[4 * k + 0] + ww.y * sff[4 * k + 1]
               + ww.z * sff[4 * k + 2] + ww.w * sff[4 * k + 3];
        }
        a = fmaxf(a, 0.f);
        float v = a * r_w2[tid];
        v += __shfl_xor(v, 1, 64);
        v += __shfl_xor(v, 2, 64);
        v += __shfl_xor(v, 4, 64);
        v += __shfl_xor(v, 8, 64);
        if (tid == 0) out[b] = v + r_b2[0];
    }
}

extern "C" void kernel_launch(void* const* d_in, const int* in_sizes, int n_in,
                              void* d_out, int out_size, void* d_ws, size_t ws_size,
                              hipStream_t stream) {
    const float* x        = (const float*)d_in[0];
    const float* Q        = (const float*)d_in[1];
    const float* sa_w_in  = (const float*)d_in[2];
    const float* sa_b_in  = (const float*)d_in[3];
    const float* sa_w_out = (const float*)d_in[4];
    const float* sa_b_out = (const float*)d_in[5];
    const float* ca_w_in  = (const float*)d_in[6];
    const float* ca_b_in  = (const float*)d_in[7];
    const float* ca_w_out = (const float*)d_in[8];
    const float* ca_b_out = (const float*)d_in[9];
    const float* r_w1     = (const float*)d_in[10];
    const float* r_b1     = (const float*)d_in[11];
    const float* r_w2     = (const float*)d_in[12];
    const float* r_b2     = (const float*)d_in[13];

    float* out = (float*)d_out;
    const int B = in_sizes[0] / (SEQ * EMB);
    float* sim = out + B;            // d_out = [out (B), similarity (B*F*S)]
    float* ws  = (float*)d_ws;       // 208 floats: wkq[64], csb[8], M0[64], M1[64], bo[8]

    precompute_kernel<<<1, 64, 0, stream>>>(Q, sa_w_in, sa_b_in, sa_w_out, sa_b_out,
                                            ca_w_in, ca_b_in, ca_w_out, ca_b_out, ws);
    fused_kernel<<<B, 256, 0, stream>>>(x, r_w1, r_b1, r_w2, r_b2, ws, out, sim);
}

// Round 3
// 439.730 us; speedup vs baseline: 1.1458x; 1.1458x over previous
//
#include <hip/hip_runtime.h>

#define SEQ 512
#define EMB 8
#define NFAC 4

typedef float v2f __attribute__((ext_vector_type(2)));

__device__ __forceinline__ float rfl(float v) {
    return __int_as_float(__builtin_amdgcn_readfirstlane(__float_as_int(v)));
}

// ---------------------------------------------------------------------------
// ws layout (floats):
//   wkq  [0..63]    folded cross-attn query·Wk rows: scores[p][s]=wkq[p]·x[s]+csb[p]
//   csb  [64..71]
//   M0   [72..135]  Wout[:,0:4]·Wv0  (8x8)  -> qcr = bo + M0·u_f + M1·u_{4+f}
//   M1   [136..199] Wout[:,4:8]·Wv1  (8x8)     where u_p = (Σ_s e_p(s)·x_s)/Σ_s e_p(s)
//   bo   [200..207] ca_b_out + Wout·bv
// ---------------------------------------------------------------------------
__global__ void precompute_kernel(
    const float* __restrict__ Q,
    const float* __restrict__ sa_w_in, const float* __restrict__ sa_b_in,
    const float* __restrict__ sa_w_out, const float* __restrict__ sa_b_out,
    const float* __restrict__ ca_w_in, const float* __restrict__ ca_b_in,
    const float* __restrict__ ca_w_out, const float* __restrict__ ca_b_out,
    float* __restrict__ ws)
{
    const int t = threadIdx.x;
    __shared__ float sw[608];
    __shared__ float sqh[32], skh[32], svh[32], sctx[32], sQu[32], sqc[32];
    enum { OQ = 0, SWIN = 32, SBIN = 224, SWOUT = 248, SBOUT = 312,
           CWIN = 320, CBIN = 512, CWOUT = 536, CBOUT = 600 };

    for (int i = t; i < 32;  i += 64) sw[OQ + i]    = Q[i];
    for (int i = t; i < 192; i += 64) sw[SWIN + i]  = sa_w_in[i];
    for (int i = t; i < 24;  i += 64) sw[SBIN + i]  = sa_b_in[i];
    for (int i = t; i < 64;  i += 64) sw[SWOUT + i] = sa_w_out[i];
    if (t < 8) sw[SBOUT + t] = sa_b_out[t];
    for (int i = t; i < 192; i += 64) sw[CWIN + i]  = ca_w_in[i];
    for (int i = t; i < 24;  i += 64) sw[CBIN + i]  = ca_b_in[i];
    for (int i = t; i < 64;  i += 64) sw[CWOUT + i] = ca_w_out[i];
    if (t < 8) sw[CBOUT + t] = ca_b_out[t];
    __syncthreads();

    {
        const int e2 = t >> 3, e = t & 7;
        float m0 = 0.f, m1 = 0.f;
        #pragma unroll
        for (int d = 0; d < 4; ++d) {
            m0 += sw[CWOUT + e2 * 8 + d]     * sw[CWIN + (16 + d) * 8 + e];
            m1 += sw[CWOUT + e2 * 8 + 4 + d] * sw[CWIN + (20 + d) * 8 + e];
        }
        ws[72 + t]  = m0;
        ws[136 + t] = m1;
    }
    if (t < 8) {
        float a = sw[CBOUT + t];
        #pragma unroll
        for (int d = 0; d < 8; ++d) a += sw[CWOUT + t * 8 + d] * sw[CBIN + 16 + d];
        ws[200 + t] = a;
    }

    if (t < 32) {
        const int l = t >> 3, j = t & 7;
        float aq = sw[SBIN + j], ak = sw[SBIN + 8 + j], av = sw[SBIN + 16 + j];
        #pragma unroll
        for (int e = 0; e < 8; ++e) {
            const float q = sw[OQ + l * 8 + e];
            aq += q * sw[SWIN + j * 8 + e];
            ak += q * sw[SWIN + (8 + j) * 8 + e];
            av += q * sw[SWIN + (16 + j) * 8 + e];
        }
        sqh[t] = aq; skh[t] = ak; svh[t] = av;
    }
    __syncthreads();

    if (t < 8) {
        const int h = t >> 2, l = t & 3;
        float sc[4], mx = -1e30f;
        #pragma unroll
        for (int m = 0; m < 4; ++m) {
            float a = 0.f;
            #pragma unroll
            for (int d = 0; d < 4; ++d) a += sqh[l * 8 + h * 4 + d] * skh[m * 8 + h * 4 + d];
            sc[m] = 0.5f * a;
            mx = fmaxf(mx, sc[m]);
        }
        float ssum = 0.f;
        #pragma unroll
        for (int m = 0; m < 4; ++m) { sc[m] = __expf(sc[m] - mx); ssum += sc[m]; }
        const float inv = 1.f / ssum;
        #pragma unroll
        for (int d = 0; d < 4; ++d) {
            float a = 0.f;
            #pragma unroll
            for (int m = 0; m < 4; ++m) a += sc[m] * svh[m * 8 + h * 4 + d];
            sctx[l * 8 + h * 4 + d] = a * inv;
        }
    }
    __syncthreads();

    if (t < 32) {
        const int l = t >> 3, e2 = t & 7;
        float a = sw[SBOUT + e2];
        #pragma unroll
        for (int e = 0; e < 8; ++e) a += sctx[l * 8 + e] * sw[SWOUT + e2 * 8 + e];
        sQu[l * 8 + e2] = a;
    }
    __syncthreads();

    if (t < 32) {
        const int l = t >> 3, j = t & 7;
        float a = sw[CBIN + j];
        #pragma unroll
        for (int e = 0; e < 8; ++e) a += sQu[l * 8 + e] * sw[CWIN + j * 8 + e];
        sqc[l * 8 + j] = a;
    }
    __syncthreads();

    {
        const int p = t >> 3, e = t & 7, h = p >> 2, f = p & 3;
        float a = 0.f;
        #pragma unroll
        for (int d = 0; d < 4; ++d)
            a += sqc[f * 8 + h * 4 + d] * sw[CWIN + (8 + h * 4 + d) * 8 + e];
        ws[p * 8 + e] = 0.5f * a;
    }
    if (t < 8) {
        const int p = t, h = p >> 2, f = p & 3;
        float a = 0.f;
        #pragma unroll
        for (int d = 0; d < 4; ++d) a += sqc[f * 8 + h * 4 + d] * sw[CBIN + 8 + h * 4 + d];
        ws[64 + p] = 0.5f * a;
    }
}

// ---------------------------------------------------------------------------
// Fused kernel: 1 block/batch, 4 waves. Wave w owns cross rows p={2w,2w+1},
// sim row f=w. x cached in registers across both passes (batched dwordx4
// loads up-front for MLP). Inner math on float2 ext-vectors -> v_pk_fma_f32.
// Two-stage wave reductions (intra-8 DPP butterfly + element select + cross).
// ---------------------------------------------------------------------------
__global__ __launch_bounds__(256, 4) void fused_kernel(
    const float* __restrict__ x,
    const float* __restrict__ r_w1, const float* __restrict__ r_b1,
    const float* __restrict__ r_w2, const float* __restrict__ r_b2,
    const float* __restrict__ ws,
    float* __restrict__ out, float* __restrict__ sim_out)
{
    const int b = blockIdx.x;
    const int tid = threadIdx.x;
    const int w = __builtin_amdgcn_readfirstlane(tid >> 6);
    const int lane = tid & 63;
    const int c7 = lane & 7;

    __shared__ float su[64];    // normalized u rows [p][e]
    __shared__ float sff[32];   // final_factors [f][e]

    const float* xb = x + (size_t)b * (SEQ * EMB);

    // wave-uniform score weights -> SGPRs
    const int p0 = 2 * w, p1 = 2 * w + 1;
    v2f wq0[4], wq1[4];
    #pragma unroll
    for (int i = 0; i < 4; ++i) {
        wq0[i] = v2f{rfl(ws[p0 * 8 + 2 * i]), rfl(ws[p0 * 8 + 2 * i + 1])};
        wq1[i] = v2f{rfl(ws[p1 * 8 + 2 * i]), rfl(ws[p1 * 8 + 2 * i + 1])};
    }
    const float cb0 = rfl(ws[64 + p0]), cb1 = rfl(ws[64 + p1]);

    // ---- batched x load: 16 dwordx4 in flight, register-cached both passes
    float4 L0[8], L1[8];
    #pragma unroll
    for (int j = 0; j < 8; ++j) {
        const float4* xp = (const float4*)(xb + (lane + 64 * j) * 8);
        L0[j] = xp[0];
        L1[j] = xp[1];
    }

    // ---- phase A: cross scores + exp + weighted-x accumulation (packed)
    v2f xa0[4] = {}, xa1[4] = {};
    float sum0 = 0.f, sum1 = 0.f;
    #pragma unroll
    for (int j = 0; j < 8; ++j) {
        v2f xv[4];
        xv[0] = v2f{L0[j].x, L0[j].y}; xv[1] = v2f{L0[j].z, L0[j].w};
        xv[2] = v2f{L1[j].x, L1[j].y}; xv[3] = v2f{L1[j].z, L1[j].w};
        v2f s0 = {cb0, 0.f}, s1 = {cb1, 0.f};
        #pragma unroll
        for (int i = 0; i < 4; ++i) { s0 += wq0[i] * xv[i]; s1 += wq1[i] * xv[i]; }
        const float e0 = __expf(s0.x + s0.y), e1 = __expf(s1.x + s1.y);
        sum0 += e0; sum1 += e1;
        #pragma unroll
        for (int i = 0; i < 4; ++i) { xa0[i] += e0 * xv[i]; xa1[i] += e1 * xv[i]; }
    }
    // two-stage reduction
    float* a0 = (float*)xa0;
    float* a1 = (float*)xa1;
    #pragma unroll
    for (int m = 1; m < 8; m <<= 1) {
        sum0 += __shfl_xor(sum0, m, 64);
        sum1 += __shfl_xor(sum1, m, 64);
        #pragma unroll
        for (int e = 0; e < 8; ++e) {
            a0[e] += __shfl_xor(a0[e], m, 64);
            a1[e] += __shfl_xor(a1[e], m, 64);
        }
    }
    float v0 = a0[0], v1 = a1[0];
    #pragma unroll
    for (int e = 1; e < 8; ++e) {
        v0 = (c7 == e) ? a0[e] : v0;
        v1 = (c7 == e) ? a1[e] : v1;
    }
    #pragma unroll
    for (int m = 8; m < 64; m <<= 1) {
        sum0 += __shfl_xor(sum0, m, 64);
        sum1 += __shfl_xor(sum1, m, 64);
        v0 += __shfl_xor(v0, m, 64);
        v1 += __shfl_xor(v1, m, 64);
    }
    if (lane < 8) {
        su[p0 * 8 + lane] = v0 / sum0;
        su[p1 * 8 + lane] = v1 / sum1;
    }
    __syncthreads();

    // ---- phase B: qcr row f=w via folded M0/M1 (8 rows computed, shfl bcast)
    float u0[8], u1[8];
    #pragma unroll
    for (int e = 0; e < 8; ++e) { u0[e] = su[w * 8 + e]; u1[e] = su[32 + w * 8 + e]; }
    float qv = ws[200 + c7];
    #pragma unroll
    for (int e = 0; e < 8; ++e)
        qv += ws[72 + c7 * 8 + e] * u0[e] + ws[136 + c7 * 8 + e] * u1[e];
    v2f qcr[4];
    #pragma unroll
    for (int i = 0; i < 4; ++i)
        qcr[i] = v2f{__shfl(qv, 2 * i, 64), __shfl(qv, 2 * i + 1, 64)};

    // ---- phase C: similarity row f=w from cached x, fused softmax + ff
    v2f fac[4] = {};
    float fsum = 0.f;
    float* simb = sim_out + (size_t)b * (NFAC * SEQ) + w * SEQ;
    #pragma unroll
    for (int j = 0; j < 8; ++j) {
        v2f xv[4];
        xv[0] = v2f{L0[j].x, L0[j].y}; xv[1] = v2f{L0[j].z, L0[j].w};
        xv[2] = v2f{L1[j].x, L1[j].y}; xv[3] = v2f{L1[j].z, L1[j].w};
        v2f sv = qcr[0] * xv[0];
        sv += qcr[1] * xv[1];
        sv += qcr[2] * xv[2];
        sv += qcr[3] * xv[3];
        const float sim = sv.x + sv.y;
        simb[lane + 64 * j] = sim;
        const float ez = __expf(sim);
        fsum += ez;
        #pragma unroll
        for (int i = 0; i < 4; ++i) fac[i] += ez * xv[i];
    }
    float* fa = (float*)fac;
    #pragma unroll
    for (int m = 1; m < 8; m <<= 1) {
        fsum += __shfl_xor(fsum, m, 64);
        #pragma unroll
        for (int e = 0; e < 8; ++e) fa[e] += __shfl_xor(fa[e], m, 64);
    }
    float fv = fa[0];
    #pragma unroll
    for (int e = 1; e < 8; ++e) fv = (c7 == e) ? fa[e] : fv;
    #pragma unroll
    for (int m = 8; m < 64; m <<= 1) {
        fsum += __shfl_xor(fsum, m, 64);
        fv += __shfl_xor(fv, m, 64);
    }
    if (lane < 8) sff[w * 8 + lane] = fv / fsum;
    __syncthreads();

    // ---- phase D: tiny MLP (wave 0, lanes 0..15), out[b]
    if (tid < 16) {
        float a = r_b1[tid];
        const float4* w1p = (const float4*)(r_w1 + tid * 32);
        #pragma unroll
        for (int k = 0; k < 8; ++k) {
            float4 ww = w1p[k];
            a += ww.x * sff[4 * k + 0] + ww.y * sff[4 * k + 1]
               + ww.z * sff[4 * k + 2] + ww.w * sff[4 * k + 3];
        }
        a = fmaxf(a, 0.f);
        float v = a * r_w2[tid];
        v += __shfl_xor(v, 1, 64);
        v += __shfl_xor(v, 2, 64);
        v += __shfl_xor(v, 4, 64);
        v += __shfl_xor(v, 8, 64);
        if (tid == 0) out[b] = v + r_b2[0];
    }
}

extern "C" void kernel_launch(void* const* d_in, const int* in_sizes, int n_in,
                              void* d_out, int out_size, void* d_ws, size_t ws_size,
                              hipStream_t stream) {
    const float* x        = (const float*)d_in[0];
    const float* Q        = (const float*)d_in[1];
    const float* sa_w_in  = (const float*)d_in[2];
    const float* sa_b_in  = (const float*)d_in[3];
    const float* sa_w_out = (const float*)d_in[4];
    const float* sa_b_out = (const float*)d_in[5];
    const float* ca_w_in  = (const float*)d_in[6];
    const float* ca_b_in  = (const float*)d_in[7];
    const float* ca_w_out = (const float*)d_in[8];
    const float* ca_b_out = (const float*)d_in[9];
    const float* r_w1     = (const float*)d_in[10];
    const float* r_b1     = (const float*)d_in[11];
    const float* r_w2     = (const float*)d_in[12];
    const float* r_b2     = (const float*)d_in[13];

    float* out = (float*)d_out;
    const int B = in_sizes[0] / (SEQ * EMB);
    float* sim = out + B;            // d_out = [out (B), similarity (B*F*S)]
    float* ws  = (float*)d_ws;       // 208 floats

    precompute_kernel<<<1, 64, 0, stream>>>(Q, sa_w_in, sa_b_in, sa_w_out, sa_b_out,
                                            ca_w_in, ca_b_in, ca_w_out, ca_b_out, ws);
    fused_kernel<<<B, 256, 0, stream>>>(x, r_w1, r_b1, r_w2, r_b2, ws, out, sim);
}

// Round 4
// 432.905 us; speedup vs baseline: 1.1639x; 1.0158x over previous
//
#include <hip/hip_runtime.h>

#define SEQ 512
#define EMB 8
#define NFAC 4

typedef float v2f __attribute__((ext_vector_type(2)));

__device__ __forceinline__ float rfl(float v) {
    return __int_as_float(__builtin_amdgcn_readfirstlane(__float_as_int(v)));
}

// padded float4-chunk index: breaks the 16B-stride bank aliasing
// (chunk c lives at c + (c>>3); every 8 consecutive reads/writes cover all
//  8 bank-groups exactly once -> conflict-free ds_read_b128/ds_write_b128)
__device__ __forceinline__ int ldsc(int c) { return c + (c >> 3); }

// ---------------------------------------------------------------------------
// ws layout (floats):
//   wkq  [0..63]    folded cross-attn query·Wk rows: scores[p][s]=wkq[p]·x[s]+csb[p]
//   csb  [64..71]
//   M0   [72..135]  Wout[:,0:4]·Wv0  (8x8)  -> qcr = bo + M0·u_f + M1·u_{4+f}
//   M1   [136..199] Wout[:,4:8]·Wv1  (8x8)     where u_p = (Σ_s e_p(s)·x_s)/Σ_s e_p(s)
//   bo   [200..207] ca_b_out + Wout·bv
// ---------------------------------------------------------------------------
__global__ void precompute_kernel(
    const float* __restrict__ Q,
    const float* __restrict__ sa_w_in, const float* __restrict__ sa_b_in,
    const float* __restrict__ sa_w_out, const float* __restrict__ sa_b_out,
    const float* __restrict__ ca_w_in, const float* __restrict__ ca_b_in,
    const float* __restrict__ ca_w_out, const float* __restrict__ ca_b_out,
    float* __restrict__ ws)
{
    const int t = threadIdx.x;
    __shared__ float sw[608];
    __shared__ float sqh[32], skh[32], svh[32], sctx[32], sQu[32], sqc[32];
    enum { OQ = 0, SWIN = 32, SBIN = 224, SWOUT = 248, SBOUT = 312,
           CWIN = 320, CBIN = 512, CWOUT = 536, CBOUT = 600 };

    for (int i = t; i < 32;  i += 64) sw[OQ + i]    = Q[i];
    for (int i = t; i < 192; i += 64) sw[SWIN + i]  = sa_w_in[i];
    for (int i = t; i < 24;  i += 64) sw[SBIN + i]  = sa_b_in[i];
    for (int i = t; i < 64;  i += 64) sw[SWOUT + i] = sa_w_out[i];
    if (t < 8) sw[SBOUT + t] = sa_b_out[t];
    for (int i = t; i < 192; i += 64) sw[CWIN + i]  = ca_w_in[i];
    for (int i = t; i < 24;  i += 64) sw[CBIN + i]  = ca_b_in[i];
    for (int i = t; i < 64;  i += 64) sw[CWOUT + i] = ca_w_out[i];
    if (t < 8) sw[CBOUT + t] = ca_b_out[t];
    __syncthreads();

    {
        const int e2 = t >> 3, e = t & 7;
        float m0 = 0.f, m1 = 0.f;
        #pragma unroll
        for (int d = 0; d < 4; ++d) {
            m0 += sw[CWOUT + e2 * 8 + d]     * sw[CWIN + (16 + d) * 8 + e];
            m1 += sw[CWOUT + e2 * 8 + 4 + d] * sw[CWIN + (20 + d) * 8 + e];
        }
        ws[72 + t]  = m0;
        ws[136 + t] = m1;
    }
    if (t < 8) {
        float a = sw[CBOUT + t];
        #pragma unroll
        for (int d = 0; d < 8; ++d) a += sw[CWOUT + t * 8 + d] * sw[CBIN + 16 + d];
        ws[200 + t] = a;
    }

    if (t < 32) {
        const int l = t >> 3, j = t & 7;
        float aq = sw[SBIN + j], ak = sw[SBIN + 8 + j], av = sw[SBIN + 16 + j];
        #pragma unroll
        for (int e = 0; e < 8; ++e) {
            const float q = sw[OQ + l * 8 + e];
            aq += q * sw[SWIN + j * 8 + e];
            ak += q * sw[SWIN + (8 + j) * 8 + e];
            av += q * sw[SWIN + (16 + j) * 8 + e];
        }
        sqh[t] = aq; skh[t] = ak; svh[t] = av;
    }
    __syncthreads();

    if (t < 8) {
        const int h = t >> 2, l = t & 3;
        float sc[4], mx = -1e30f;
        #pragma unroll
        for (int m = 0; m < 4; ++m) {
            float a = 0.f;
            #pragma unroll
            for (int d = 0; d < 4; ++d) a += sqh[l * 8 + h * 4 + d] * skh[m * 8 + h * 4 + d];
            sc[m] = 0.5f * a;
            mx = fmaxf(mx, sc[m]);
        }
        float ssum = 0.f;
        #pragma unroll
        for (int m = 0; m < 4; ++m) { sc[m] = __expf(sc[m] - mx); ssum += sc[m]; }
        const float inv = 1.f / ssum;
        #pragma unroll
        for (int d = 0; d < 4; ++d) {
            float a = 0.f;
            #pragma unroll
            for (int m = 0; m < 4; ++m) a += sc[m] * svh[m * 8 + h * 4 + d];
            sctx[l * 8 + h * 4 + d] = a * inv;
        }
    }
    __syncthreads();

    if (t < 32) {
        const int l = t >> 3, e2 = t & 7;
        float a = sw[SBOUT + e2];
        #pragma unroll
        for (int e = 0; e < 8; ++e) a += sctx[l * 8 + e] * sw[SWOUT + e2 * 8 + e];
        sQu[l * 8 + e2] = a;
    }
    __syncthreads();

    if (t < 32) {
        const int l = t >> 3, j = t & 7;
        float a = sw[CBIN + j];
        #pragma unroll
        for (int e = 0; e < 8; ++e) a += sQu[l * 8 + e] * sw[CWIN + j * 8 + e];
        sqc[l * 8 + j] = a;
    }
    __syncthreads();

    {
        const int p = t >> 3, e = t & 7, h = p >> 2, f = p & 3;
        float a = 0.f;
        #pragma unroll
        for (int d = 0; d < 4; ++d)
            a += sqc[f * 8 + h * 4 + d] * sw[CWIN + (8 + h * 4 + d) * 8 + e];
        ws[p * 8 + e] = 0.5f * a;
    }
    if (t < 8) {
        const int p = t, h = p >> 2, f = p & 3;
        float a = 0.f;
        #pragma unroll
        for (int d = 0; d < 4; ++d) a += sqc[f * 8 + h * 4 + d] * sw[CBIN + 8 + h * 4 + d];
        ws[64 + p] = 0.5f * a;
    }
}

// ---------------------------------------------------------------------------
// Fused kernel: 1 block/batch, 4 waves, x staged ONCE into LDS (pad-swizzled,
// bank-conflict-free) and shared by all waves/phases. VGPR-light -> 8 blocks/CU.
// Wave w owns cross rows p={2w,2w+1}, sim row f=w. Packed fp32 math.
// ---------------------------------------------------------------------------
__global__ __launch_bounds__(256, 8) void fused_kernel(
    const float* __restrict__ x,
    const float* __restrict__ r_w1, const float* __restrict__ r_b1,
    const float* __restrict__ r_w2, const float* __restrict__ r_b2,
    const float* __restrict__ ws,
    float* __restrict__ out, float* __restrict__ sim_out)
{
    const int b = blockIdx.x;
    const int tid = threadIdx.x;
    const int w = __builtin_amdgcn_readfirstlane(tid >> 6);
    const int lane = tid & 63;
    const int c7 = lane & 7;

    __shared__ float4 sx[1152];  // 1024 chunks + 128 pad (18.0 KB)
    __shared__ float su[64];     // normalized u rows [p][e]
    __shared__ float sff[32];    // final_factors [f][e]

    const float* xb = x + (size_t)b * (SEQ * EMB);

    // ---- cooperative x fill: 4 coalesced dwordx4 per thread
    {
        const float4* xg = (const float4*)xb;
        #pragma unroll
        for (int i = 0; i < 4; ++i) {
            const int c = tid + 256 * i;
            sx[ldsc(c)] = xg[c];
        }
    }

    // wave-uniform score weights -> SGPRs
    const int p0 = 2 * w, p1 = 2 * w + 1;
    v2f wq0[4], wq1[4];
    #pragma unroll
    for (int i = 0; i < 4; ++i) {
        wq0[i] = v2f{rfl(ws[p0 * 8 + 2 * i]), rfl(ws[p0 * 8 + 2 * i + 1])};
        wq1[i] = v2f{rfl(ws[p1 * 8 + 2 * i]), rfl(ws[p1 * 8 + 2 * i + 1])};
    }
    const float cb0 = rfl(ws[64 + p0]), cb1 = rfl(ws[64 + p1]);
    __syncthreads();

    // ---- phase A: cross scores + exp + weighted-x accumulation (packed)
    v2f xa0[4] = {}, xa1[4] = {};
    float sum0 = 0.f, sum1 = 0.f;
    #pragma unroll
    for (int j = 0; j < 8; ++j) {
        const int s = lane + 64 * j;
        const float4 lo = sx[ldsc(2 * s)];
        const float4 hi = sx[ldsc(2 * s + 1)];
        v2f xv[4];
        xv[0] = v2f{lo.x, lo.y}; xv[1] = v2f{lo.z, lo.w};
        xv[2] = v2f{hi.x, hi.y}; xv[3] = v2f{hi.z, hi.w};
        v2f s0 = {cb0, 0.f}, s1 = {cb1, 0.f};
        #pragma unroll
        for (int i = 0; i < 4; ++i) { s0 += wq0[i] * xv[i]; s1 += wq1[i] * xv[i]; }
        const float e0 = __expf(s0.x + s0.y), e1 = __expf(s1.x + s1.y);
        sum0 += e0; sum1 += e1;
        #pragma unroll
        for (int i = 0; i < 4; ++i) { xa0[i] += e0 * xv[i]; xa1[i] += e1 * xv[i]; }
    }
    // two-stage reduction
    float* a0 = (float*)xa0;
    float* a1 = (float*)xa1;
    #pragma unroll
    for (int m = 1; m < 8; m <<= 1) {
        sum0 += __shfl_xor(sum0, m, 64);
        sum1 += __shfl_xor(sum1, m, 64);
        #pragma unroll
        for (int e = 0; e < 8; ++e) {
            a0[e] += __shfl_xor(a0[e], m, 64);
            a1[e] += __shfl_xor(a1[e], m, 64);
        }
    }
    float v0 = a0[0], v1 = a1[0];
    #pragma unroll
    for (int e = 1; e < 8; ++e) {
        v0 = (c7 == e) ? a0[e] : v0;
        v1 = (c7 == e) ? a1[e] : v1;
    }
    #pragma unroll
    for (int m = 8; m < 64; m <<= 1) {
        sum0 += __shfl_xor(sum0, m, 64);
        sum1 += __shfl_xor(sum1, m, 64);
        v0 += __shfl_xor(v0, m, 64);
        v1 += __shfl_xor(v1, m, 64);
    }
    if (lane < 8) {
        su[p0 * 8 + lane] = v0 / sum0;
        su[p1 * 8 + lane] = v1 / sum1;
    }
    __syncthreads();

    // ---- phase B: qcr row f=w via folded M0/M1 (8 rows computed, shfl bcast)
    float u0[8], u1[8];
    #pragma unroll
    for (int e = 0; e < 8; ++e) { u0[e] = su[w * 8 + e]; u1[e] = su[32 + w * 8 + e]; }
    float qv = ws[200 + c7];
    #pragma unroll
    for (int e = 0; e < 8; ++e)
        qv += ws[72 + c7 * 8 + e] * u0[e] + ws[136 + c7 * 8 + e] * u1[e];
    v2f qcr[4];
    #pragma unroll
    for (int i = 0; i < 4; ++i)
        qcr[i] = v2f{__shfl(qv, 2 * i, 64), __shfl(qv, 2 * i + 1, 64)};

    // ---- phase C: similarity row f=w from LDS x, fused softmax + ff
    v2f fac[4] = {};
    float fsum = 0.f;
    float* simb = sim_out + (size_t)b * (NFAC * SEQ) + w * SEQ;
    #pragma unroll
    for (int j = 0; j < 8; ++j) {
        const int s = lane + 64 * j;
        const float4 lo = sx[ldsc(2 * s)];
        const float4 hi = sx[ldsc(2 * s + 1)];
        v2f xv[4];
        xv[0] = v2f{lo.x, lo.y}; xv[1] = v2f{lo.z, lo.w};
        xv[2] = v2f{hi.x, hi.y}; xv[3] = v2f{hi.z, hi.w};
        v2f sv = qcr[0] * xv[0];
        sv += qcr[1] * xv[1];
        sv += qcr[2] * xv[2];
        sv += qcr[3] * xv[3];
        const float sim = sv.x + sv.y;
        simb[s] = sim;
        const float ez = __expf(sim);
        fsum += ez;
        #pragma unroll
        for (int i = 0; i < 4; ++i) fac[i] += ez * xv[i];
    }
    float* fa = (float*)fac;
    #pragma unroll
    for (int m = 1; m < 8; m <<= 1) {
        fsum += __shfl_xor(fsum, m, 64);
        #pragma unroll
        for (int e = 0; e < 8; ++e) fa[e] += __shfl_xor(fa[e], m, 64);
    }
    float fv = fa[0];
    #pragma unroll
    for (int e = 1; e < 8; ++e) fv = (c7 == e) ? fa[e] : fv;
    #pragma unroll
    for (int m = 8; m < 64; m <<= 1) {
        fsum += __shfl_xor(fsum, m, 64);
        fv += __shfl_xor(fv, m, 64);
    }
    if (lane < 8) sff[w * 8 + lane] = fv / fsum;
    __syncthreads();

    // ---- phase D: tiny MLP (wave 0, lanes 0..15), out[b]
    if (tid < 16) {
        float a = r_b1[tid];
        const float4* w1p = (const float4*)(r_w1 + tid * 32);
        #pragma unroll
        for (int k = 0; k < 8; ++k) {
            float4 ww = w1p[k];
            a += ww.x * sff[4 * k + 0] + ww.y * sff[4 * k + 1]
               + ww.z * sff[4 * k + 2] + ww.w * sff[4 * k + 3];
        }
        a = fmaxf(a, 0.f);
        float v = a * r_w2[tid];
        v += __shfl_xor(v, 1, 64);
        v += __shfl_xor(v, 2, 64);
        v += __shfl_xor(v, 4, 64);
        v += __shfl_xor(v, 8, 64);
        if (tid == 0) out[b] = v + r_b2[0];
    }
}

extern "C" void kernel_launch(void* const* d_in, const int* in_sizes, int n_in,
                              void* d_out, int out_size, void* d_ws, size_t ws_size,
                              hipStream_t stream) {
    const float* x        = (const float*)d_in[0];
    const float* Q        = (const float*)d_in[1];
    const float* sa_w_in  = (const float*)d_in[2];
    const float* sa_b_in  = (const float*)d_in[3];
    const float* sa_w_out = (const float*)d_in[4];
    const float* sa_b_out = (const float*)d_in[5];
    const float* ca_w_in  = (const float*)d_in[6];
    const float* ca_b_in  = (const float*)d_in[7];
    const float* ca_w_out = (const float*)d_in[8];
    const float* ca_b_out = (const float*)d_in[9];
    const float* r_w1     = (const float*)d_in[10];
    const float* r_b1     = (const float*)d_in[11];
    const float* r_w2     = (const float*)d_in[12];
    const float* r_b2     = (const float*)d_in[13];

    float* out = (float*)d_out;
    const int B = in_sizes[0] / (SEQ * EMB);
    float* sim = out + B;            // d_out = [out (B), similarity (B*F*S)]
    float* ws  = (float*)d_ws;       // 208 floats

    precompute_kernel<<<1, 64, 0, stream>>>(Q, sa_w_in, sa_b_in, sa_w_out, sa_b_out,
                                            ca_w_in, ca_b_in, ca_w_out, ca_b_out, ws);
    fused_kernel<<<B, 256, 0, stream>>>(x, r_w1, r_b1, r_w2, r_b2, ws, out, sim);
}